// Round 15
// baseline (309.840 us; speedup 1.0000x reference)
//
#include <hip/hip_runtime.h>
#include <hip/hip_fp16.h>

typedef _Float16 f16x8 __attribute__((ext_vector_type(8)));
typedef _Float16 f16x4 __attribute__((ext_vector_type(4)));
typedef _Float16 f16x2 __attribute__((ext_vector_type(2)));
typedef float    f32x16 __attribute__((ext_vector_type(16)));
typedef float    f32x4 __attribute__((ext_vector_type(4)));

#define SH 264   // H row stride (fp16): 256+8
#define SE 56    // E row stride (fp16)
#define PTS 128  // points per block

struct LayerPtrs {
  const float* w[8];
  const float* b[8];
};

// Weight fragments in d_ws, A-operand layout for mfma_f32_32x32x16_f16:
//   m = mtile*32 + (lane&31), k = kc*16 + (lane>>5)*8 + j ; value = W[k][m]
// index = WOFF[l] + (kc*8 + mtile)*64 + lane, element j.
__global__ void prep_weights(LayerPtrs P, f16x8* __restrict__ wf) {
  int gid = blockIdx.x * 256 + threadIdx.x;
  if (gid >= 60416) return;
  const int OFF[9] = {0,1536,9728,17920,26112,35840,44032,52224,60416};
  int l = 0;
  while (gid >= OFF[l+1]) ++l;
  int f = gid - OFF[l];
  int lane = f & 63;
  int t = f >> 6;
  int mtile = t & 7;
  int kc = t >> 3;
  int col = mtile * 32 + (lane & 31);
  int kb  = (lane >> 5) * 8;
  const float* w = P.w[l];
  f16x8 v;
#pragma unroll
  for (int j = 0; j < 8; ++j) {
    float x = 0.f;
    if (l == 4) {
      if (kc < 3) {
        int k = kc * 16 + kb + j;
        if (k < 39) x = w[k * 256 + col];
      } else {
        int k = (kc - 3) * 16 + kb + j;
        x = w[(39 + k) * 256 + col];
      }
    } else if (l == 0) {
      int k = kc * 16 + kb + j;
      if (k < 39) x = w[k * 256 + col];
    } else {
      int k = kc * 16 + kb + j;
      x = w[k * 256 + col];
    }
    v[j] = (_Float16)x;
  }
  wf[gid] = v;
}

struct WPre  { f16x8 a0, a1; };     // kc0 weight frags (2 m-tiles)
struct BTile { f32x16 t[2]; };      // bias (or wsdf) tile in C-layout, per m-tile

__device__ __forceinline__ WPre wpre(const f16x8* __restrict__ wb) {
  WPre p; p.a0 = wb[0]; p.a1 = wb[64]; return p;
}

// C/D reg 4g+r holds hidden mt*32+8g+4h+r; tile mirrors that (nt-independent).
__device__ __forceinline__ BTile bias_tile(const float* __restrict__ bp, int h) {
  BTile r;
#pragma unroll
  for (int mt = 0; mt < 2; ++mt)
#pragma unroll
    for (int g = 0; g < 4; ++g) {
      f32x4 q = *(const f32x4*)&bp[mt * 32 + 8 * g + 4 * h];
#pragma unroll
      for (int rr = 0; rr < 4; ++rr) r.t[mt][4 * g + rr] = q[rr];
    }
  return r;
}

#define MFMA __builtin_amdgcn_mfma_f32_32x32x16_f16

// Wave = 64 hidden (2 m-tiles) x 128 points (4 n-tiles): 8 MFMA per kc.
// Hand-pipelined: kc+1's loads issue before kc's MFMAs.
// FIRST: kc0 uses the bias tile as the C operand. PRE: kc0 a-frags pre-loaded.
template<int NKC, bool FIRST, bool PRE>
__device__ __forceinline__ void mm(const f16x8* __restrict__ wb,
                                   const _Float16* __restrict__ b0,
                                   const _Float16* __restrict__ b1,
                                   const _Float16* __restrict__ b2,
                                   const _Float16* __restrict__ b3,
                                   f32x16 acc[2][4], const BTile& bt, WPre p) {
  f16x8 a0 = PRE ? p.a0 : wb[0];
  f16x8 a1 = PRE ? p.a1 : wb[64];
  f16x8 v0 = *(const f16x8*)(b0);
  f16x8 v1 = *(const f16x8*)(b1);
  f16x8 v2 = *(const f16x8*)(b2);
  f16x8 v3 = *(const f16x8*)(b3);
#pragma unroll
  for (int kc = 0; kc < NKC; ++kc) {
    f16x8 na0, na1, nv0, nv1, nv2, nv3;
    if (kc + 1 < NKC) {
      na0 = wb[((kc + 1) * 8 + 0) * 64];
      na1 = wb[((kc + 1) * 8 + 1) * 64];
      nv0 = *(const f16x8*)(b0 + (kc + 1) * 16);
      nv1 = *(const f16x8*)(b1 + (kc + 1) * 16);
      nv2 = *(const f16x8*)(b2 + (kc + 1) * 16);
      nv3 = *(const f16x8*)(b3 + (kc + 1) * 16);
    }
    if (FIRST && kc == 0) {
      acc[0][0] = MFMA(a0, v0, bt.t[0], 0, 0, 0);
      acc[0][1] = MFMA(a0, v1, bt.t[0], 0, 0, 0);
      acc[0][2] = MFMA(a0, v2, bt.t[0], 0, 0, 0);
      acc[0][3] = MFMA(a0, v3, bt.t[0], 0, 0, 0);
      acc[1][0] = MFMA(a1, v0, bt.t[1], 0, 0, 0);
      acc[1][1] = MFMA(a1, v1, bt.t[1], 0, 0, 0);
      acc[1][2] = MFMA(a1, v2, bt.t[1], 0, 0, 0);
      acc[1][3] = MFMA(a1, v3, bt.t[1], 0, 0, 0);
    } else {
      acc[0][0] = MFMA(a0, v0, acc[0][0], 0, 0, 0);
      acc[0][1] = MFMA(a0, v1, acc[0][1], 0, 0, 0);
      acc[0][2] = MFMA(a0, v2, acc[0][2], 0, 0, 0);
      acc[0][3] = MFMA(a0, v3, acc[0][3], 0, 0, 0);
      acc[1][0] = MFMA(a1, v0, acc[1][0], 0, 0, 0);
      acc[1][1] = MFMA(a1, v1, acc[1][1], 0, 0, 0);
      acc[1][2] = MFMA(a1, v2, acc[1][2], 0, 0, 0);
      acc[1][3] = MFMA(a1, v3, acc[1][3], 0, 0, 0);
    }
    if (kc + 1 < NKC) {
      a0 = na0; a1 = na1;
      v0 = nv0; v1 = nv1; v2 = nv2; v3 = nv3;
    }
  }
}

// Epilogue: packed cvt then packed f16 relu (bias already in acc).
__device__ __forceinline__ f16x4 relu_cvt4(float a0, float a1, float a2, float a3) {
  f16x2 lo = __builtin_bit_cast(f16x2, __builtin_amdgcn_cvt_pkrtz(a0, a1));
  f16x2 hi = __builtin_bit_cast(f16x2, __builtin_amdgcn_cvt_pkrtz(a2, a3));
  union { f16x4 v; f16x2 h[2]; } u;
  u.h[0] = lo; u.h[1] = hi;
  f16x4 z = {};
  return __builtin_elementwise_max(u.v, z);
}

// C/D 32x32: col(point) = lane&31, row(hidden) = (reg&3) + 8*(reg>>2) + 4*(lane>>5)
__device__ __forceinline__ void store_act(f32x16 acc[2][4], int wg,
                                          int lane, _Float16* __restrict__ H) {
  int p0 = lane & 31, h = lane >> 5;
#pragma unroll
  for (int mt = 0; mt < 2; ++mt) {
    int hb = wg * 64 + mt * 32 + 4 * h;
#pragma unroll
    for (int g = 0; g < 4; ++g) {
#pragma unroll
      for (int nt = 0; nt < 4; ++nt) {
        f16x4 o = relu_cvt4(acc[mt][nt][4 * g + 0], acc[mt][nt][4 * g + 1],
                            acc[mt][nt][4 * g + 2], acc[mt][nt][4 * g + 3]);
        *(f16x4*)&H[(nt * 32 + p0) * SH + hb + 8 * g] = o;
      }
    }
  }
}

__global__ __launch_bounds__(256, 2)
void mlp_fused(const float* __restrict__ points,
               LayerPtrs P,
               const f16x8* __restrict__ wf,
               const float* __restrict__ wsdf,
               const float* __restrict__ bsdf,
               float* __restrict__ out) {
  __shared__ __align__(16) _Float16 H[PTS * SH];   // 67584 B
  __shared__ __align__(16) _Float16 E[PTS * SE];   // 14336 B -> 81920 total, 2 blocks/CU
  const int tid = threadIdx.x;
  const int blk = blockIdx.x;

  const int lane = tid & 63;
  const int wg   = tid >> 6;          // wave -> hidden slice [64*wg, 64*wg+64)
  const int p0   = lane & 31;
  const int h    = lane >> 5;

  const f16x8* wb = wf + (wg * 2) * 64 + lane;   // + WOFF[l] + (kc*8+mt)*64
  const int WOFF[8] = {0,1536,9728,17920,26112,35840,44032,52224};

  // Prefetch L0 weights + bias tile before the (long) embedding VALU phase.
  WPre  wp = wpre(wb + WOFF[0]);
  BTile bt = bias_tile(P.b[0] + wg * 64, h);

  // ---- embedding into E: cols 0..38 = [sin(18)|cos(18)|xyz], 39..55 zero ----
  if (tid < PTS) {
    int p = blk * PTS + tid;
    float xyz[3] = {points[p * 3 + 0], points[p * 3 + 1], points[p * 3 + 2]};
    _Float16* row = &E[tid * SE];
#pragma unroll
    for (int c = 0; c < 3; ++c) {
      float fr = 1.f;
#pragma unroll
      for (int k = 0; k < 6; ++k) {
        float e = xyz[c] * fr;
        row[c * 6 + k]      = (_Float16)sinf(e);
        row[18 + c * 6 + k] = (_Float16)cosf(e);
        fr *= 2.f;
      }
      row[36 + c] = (_Float16)xyz[c];
    }
#pragma unroll
    for (int c = 39; c < SE; ++c) row[c] = (_Float16)0.f;
  }
  __syncthreads();

  const _Float16* e0 = &E[p0 * SE + h * 8];
  const _Float16* e1 = &E[(32 + p0) * SE + h * 8];
  const _Float16* e2 = &E[(64 + p0) * SE + h * 8];
  const _Float16* e3 = &E[(96 + p0) * SE + h * 8];
  const _Float16* h0 = &H[p0 * SH + h * 8];
  const _Float16* h1 = &H[(32 + p0) * SH + h * 8];
  const _Float16* h2 = &H[(64 + p0) * SH + h * 8];
  const _Float16* h3 = &H[(96 + p0) * SH + h * 8];

  f32x16 acc[2][4];

  // L0: read E, write H (disjoint -> no barrier between mm and store)
  mm<3, true, true>(wb + WOFF[0], e0, e1, e2, e3, acc, bt, wp);
  bt = bias_tile(P.b[1] + wg * 64, h);    // next-layer bias tile, pre-barrier
  wp = wpre(wb + WOFF[1]);                // next-layer kc0 weights
  store_act(acc, wg, lane, H);
  __syncthreads();

  // L1..L3: in-place H
#pragma unroll
  for (int l = 1; l < 4; ++l) {
    mm<16, true, true>(wb + WOFF[l], h0, h1, h2, h3, acc, bt, wp);
    bt = bias_tile(P.b[l + 1] + wg * 64, h);
    wp = wpre(wb + WOFF[l + 1]);
    __syncthreads();
    store_act(acc, wg, lane, H);
    __syncthreads();
  }

  // L4: concat input = E (3 kc, bias-C + prefetched) + H (16 kc, accumulate)
  mm<3, true, true>(wb + WOFF[4], e0, e1, e2, e3, acc, bt, wp);
  mm<16, false, false>(wb + WOFF[4] + 3 * 512, h0, h1, h2, h3, acc, bt, wp);
  bt = bias_tile(P.b[5] + wg * 64, h);
  wp = wpre(wb + WOFF[5]);
  __syncthreads();
  store_act(acc, wg, lane, H);
  __syncthreads();

  // L5..L6
#pragma unroll
  for (int l = 5; l < 7; ++l) {
    mm<16, true, true>(wb + WOFF[l], h0, h1, h2, h3, acc, bt, wp);
    bt = bias_tile(P.b[l + 1] + wg * 64, h);
    wp = wpre(wb + WOFF[l + 1]);
    __syncthreads();
    store_act(acc, wg, lane, H);
    __syncthreads();
  }

  // L7 + SDF head fused: no H round-trip. out[p] = sum_h relu(x7)[p][h]*wsdf[h] + bsdf.
  mm<16, true, true>(wb + WOFF[7], h0, h1, h2, h3, acc, bt, wp);
  {
    BTile wt = bias_tile(wsdf + wg * 64, h);   // wsdf gather in C-layout
    float part[4];
#pragma unroll
    for (int nt = 0; nt < 4; ++nt) {
      float s = 0.f;
#pragma unroll
      for (int mt = 0; mt < 2; ++mt)
#pragma unroll
        for (int i = 0; i < 16; ++i)
          s += fmaxf(acc[mt][nt][i], 0.f) * wt.t[mt][i];
      part[nt] = s;
    }
    // E space is dead (last read at L4) -> partial buffer [8][128] floats (4 KB)
    float* PB = (float*)E;
    __syncthreads();   // all L7 reads of H/E done before reuse of E
#pragma unroll
    for (int nt = 0; nt < 4; ++nt)
      PB[(wg * 2 + h) * 128 + nt * 32 + p0] = part[nt];
    __syncthreads();
    if (tid < PTS) {
      float s = bsdf[0];
#pragma unroll
      for (int j = 0; j < 8; ++j) s += PB[j * 128 + tid];
      out[blk * PTS + tid] = s;
    }
  }
}

extern "C" void kernel_launch(void* const* d_in, const int* in_sizes, int n_in,
                              void* d_out, int out_size, void* d_ws, size_t ws_size,
                              hipStream_t stream) {
  const float* points = (const float*)d_in[0];
  LayerPtrs P;
  for (int i = 0; i < 8; ++i) {
    P.w[i] = (const float*)d_in[1 + 2 * i];
    P.b[i] = (const float*)d_in[2 + 2 * i];
  }
  const float* wsdf = (const float*)d_in[17];
  const float* bsdf = (const float*)d_in[18];
  f16x8* wf = (f16x8*)d_ws;   // needs 966656 B

  int N = in_sizes[0] / 3;    // 262144
  prep_weights<<<236, 256, 0, stream>>>(P, wf);
  mlp_fused<<<N / PTS, 256, 0, stream>>>(points, P, wf, wsdf, bsdf, (float*)d_out);
}

// Round 16
// 300.632 us; speedup vs baseline: 1.0306x; 1.0306x over previous
//
#include <hip/hip_runtime.h>
#include <hip/hip_fp16.h>

typedef _Float16 f16x8 __attribute__((ext_vector_type(8)));
typedef _Float16 f16x4 __attribute__((ext_vector_type(4)));
typedef _Float16 f16x2 __attribute__((ext_vector_type(2)));
typedef float    f32x16 __attribute__((ext_vector_type(16)));
typedef float    f32x4 __attribute__((ext_vector_type(4)));

#define SH 264   // H row stride (fp16): 256+8
#define SE 56    // E row stride (fp16)
#define PTS 128  // points per block

struct LayerPtrs {
  const float* w[8];
  const float* b[8];
};

// Weight fragments in d_ws, A-operand layout for mfma_f32_32x32x16_f16:
//   m = mtile*32 + (lane&31), k = kc*16 + (lane>>5)*8 + j ; value = W[k][m]
// index = WOFF[l] + (kc*8 + mtile)*64 + lane, element j.
__global__ void prep_weights(LayerPtrs P, f16x8* __restrict__ wf) {
  int gid = blockIdx.x * 256 + threadIdx.x;
  if (gid >= 60416) return;
  const int OFF[9] = {0,1536,9728,17920,26112,35840,44032,52224,60416};
  int l = 0;
  while (gid >= OFF[l+1]) ++l;
  int f = gid - OFF[l];
  int lane = f & 63;
  int t = f >> 6;
  int mtile = t & 7;
  int kc = t >> 3;
  int col = mtile * 32 + (lane & 31);
  int kb  = (lane >> 5) * 8;
  const float* w = P.w[l];
  f16x8 v;
#pragma unroll
  for (int j = 0; j < 8; ++j) {
    float x = 0.f;
    if (l == 4) {
      if (kc < 3) {
        int k = kc * 16 + kb + j;
        if (k < 39) x = w[k * 256 + col];
      } else {
        int k = (kc - 3) * 16 + kb + j;
        x = w[(39 + k) * 256 + col];
      }
    } else if (l == 0) {
      int k = kc * 16 + kb + j;
      if (k < 39) x = w[k * 256 + col];
    } else {
      int k = kc * 16 + kb + j;
      x = w[k * 256 + col];
    }
    v[j] = (_Float16)x;
  }
  wf[gid] = v;
}

struct WPre  { f16x8 a0, a1; };     // kc0 weight frags (2 m-tiles)
struct BTile { f32x16 t[2]; };      // bias tile in C-layout, per m-tile

__device__ __forceinline__ WPre wpre(const f16x8* __restrict__ wb) {
  WPre p; p.a0 = wb[0]; p.a1 = wb[64]; return p;
}

// C/D reg 4g+r holds hidden mt*32+8g+4h+r; tile mirrors that (nt-independent).
__device__ __forceinline__ BTile bias_tile(const float* __restrict__ bp, int h) {
  BTile r;
#pragma unroll
  for (int mt = 0; mt < 2; ++mt)
#pragma unroll
    for (int g = 0; g < 4; ++g) {
      f32x4 q = *(const f32x4*)&bp[mt * 32 + 8 * g + 4 * h];
#pragma unroll
      for (int rr = 0; rr < 4; ++rr) r.t[mt][4 * g + rr] = q[rr];
    }
  return r;
}

#define MFMA __builtin_amdgcn_mfma_f32_32x32x16_f16

// Wave = 64 hidden (2 m-tiles) x 128 points (4 n-tiles): 8 MFMA per kc.
// PIPE: hand-pipelined (kc+1's loads issue before kc's MFMAs).
// FIRST: kc0 uses the bias tile as the C operand. PRE: kc0 a-frags pre-loaded.
template<int NKC, bool FIRST, bool PRE, bool PIPE>
__device__ __forceinline__ void mm(const f16x8* __restrict__ wb,
                                   const _Float16* __restrict__ b0,
                                   const _Float16* __restrict__ b1,
                                   const _Float16* __restrict__ b2,
                                   const _Float16* __restrict__ b3,
                                   f32x16 acc[2][4], const BTile& bt, WPre p) {
  if (PIPE) {
    f16x8 a0 = PRE ? p.a0 : wb[0];
    f16x8 a1 = PRE ? p.a1 : wb[64];
    f16x8 v0 = *(const f16x8*)(b0);
    f16x8 v1 = *(const f16x8*)(b1);
    f16x8 v2 = *(const f16x8*)(b2);
    f16x8 v3 = *(const f16x8*)(b3);
#pragma unroll
    for (int kc = 0; kc < NKC; ++kc) {
      f16x8 na0, na1, nv0, nv1, nv2, nv3;
      if (kc + 1 < NKC) {
        na0 = wb[((kc + 1) * 8 + 0) * 64];
        na1 = wb[((kc + 1) * 8 + 1) * 64];
        nv0 = *(const f16x8*)(b0 + (kc + 1) * 16);
        nv1 = *(const f16x8*)(b1 + (kc + 1) * 16);
        nv2 = *(const f16x8*)(b2 + (kc + 1) * 16);
        nv3 = *(const f16x8*)(b3 + (kc + 1) * 16);
      }
      if (FIRST && kc == 0) {
        acc[0][0] = MFMA(a0, v0, bt.t[0], 0, 0, 0);
        acc[0][1] = MFMA(a0, v1, bt.t[0], 0, 0, 0);
        acc[0][2] = MFMA(a0, v2, bt.t[0], 0, 0, 0);
        acc[0][3] = MFMA(a0, v3, bt.t[0], 0, 0, 0);
        acc[1][0] = MFMA(a1, v0, bt.t[1], 0, 0, 0);
        acc[1][1] = MFMA(a1, v1, bt.t[1], 0, 0, 0);
        acc[1][2] = MFMA(a1, v2, bt.t[1], 0, 0, 0);
        acc[1][3] = MFMA(a1, v3, bt.t[1], 0, 0, 0);
      } else {
        acc[0][0] = MFMA(a0, v0, acc[0][0], 0, 0, 0);
        acc[0][1] = MFMA(a0, v1, acc[0][1], 0, 0, 0);
        acc[0][2] = MFMA(a0, v2, acc[0][2], 0, 0, 0);
        acc[0][3] = MFMA(a0, v3, acc[0][3], 0, 0, 0);
        acc[1][0] = MFMA(a1, v0, acc[1][0], 0, 0, 0);
        acc[1][1] = MFMA(a1, v1, acc[1][1], 0, 0, 0);
        acc[1][2] = MFMA(a1, v2, acc[1][2], 0, 0, 0);
        acc[1][3] = MFMA(a1, v3, acc[1][3], 0, 0, 0);
      }
      if (kc + 1 < NKC) {
        a0 = na0; a1 = na1;
        v0 = nv0; v1 = nv1; v2 = nv2; v3 = nv3;
      }
    }
  } else {
#pragma unroll
    for (int kc = 0; kc < NKC; ++kc) {
      f16x8 a0 = (PRE && kc == 0) ? p.a0 : wb[(kc * 8 + 0) * 64];
      f16x8 a1 = (PRE && kc == 0) ? p.a1 : wb[(kc * 8 + 1) * 64];
      f16x8 v0 = *(const f16x8*)(b0 + kc * 16);
      f16x8 v1 = *(const f16x8*)(b1 + kc * 16);
      f16x8 v2 = *(const f16x8*)(b2 + kc * 16);
      f16x8 v3 = *(const f16x8*)(b3 + kc * 16);
      if (FIRST && kc == 0) {
        acc[0][0] = MFMA(a0, v0, bt.t[0], 0, 0, 0);
        acc[0][1] = MFMA(a0, v1, bt.t[0], 0, 0, 0);
        acc[0][2] = MFMA(a0, v2, bt.t[0], 0, 0, 0);
        acc[0][3] = MFMA(a0, v3, bt.t[0], 0, 0, 0);
        acc[1][0] = MFMA(a1, v0, bt.t[1], 0, 0, 0);
        acc[1][1] = MFMA(a1, v1, bt.t[1], 0, 0, 0);
        acc[1][2] = MFMA(a1, v2, bt.t[1], 0, 0, 0);
        acc[1][3] = MFMA(a1, v3, bt.t[1], 0, 0, 0);
      } else {
        acc[0][0] = MFMA(a0, v0, acc[0][0], 0, 0, 0);
        acc[0][1] = MFMA(a0, v1, acc[0][1], 0, 0, 0);
        acc[0][2] = MFMA(a0, v2, acc[0][2], 0, 0, 0);
        acc[0][3] = MFMA(a0, v3, acc[0][3], 0, 0, 0);
        acc[1][0] = MFMA(a1, v0, acc[1][0], 0, 0, 0);
        acc[1][1] = MFMA(a1, v1, acc[1][1], 0, 0, 0);
        acc[1][2] = MFMA(a1, v2, acc[1][2], 0, 0, 0);
        acc[1][3] = MFMA(a1, v3, acc[1][3], 0, 0, 0);
      }
    }
  }
}

// Epilogue: packed cvt then packed f16 relu (bias already in acc).
__device__ __forceinline__ f16x4 relu_cvt4(float a0, float a1, float a2, float a3) {
  f16x2 lo = __builtin_bit_cast(f16x2, __builtin_amdgcn_cvt_pkrtz(a0, a1));
  f16x2 hi = __builtin_bit_cast(f16x2, __builtin_amdgcn_cvt_pkrtz(a2, a3));
  union { f16x4 v; f16x2 h[2]; } u;
  u.h[0] = lo; u.h[1] = hi;
  f16x4 z = {};
  return __builtin_elementwise_max(u.v, z);
}

// C/D 32x32: col(point) = lane&31, row(hidden) = (reg&3) + 8*(reg>>2) + 4*(lane>>5)
__device__ __forceinline__ void store_act(f32x16 acc[2][4], int wg,
                                          int lane, _Float16* __restrict__ H) {
  int p0 = lane & 31, h = lane >> 5;
#pragma unroll
  for (int mt = 0; mt < 2; ++mt) {
    int hb = wg * 64 + mt * 32 + 4 * h;
#pragma unroll
    for (int g = 0; g < 4; ++g) {
#pragma unroll
      for (int nt = 0; nt < 4; ++nt) {
        f16x4 o = relu_cvt4(acc[mt][nt][4 * g + 0], acc[mt][nt][4 * g + 1],
                            acc[mt][nt][4 * g + 2], acc[mt][nt][4 * g + 3]);
        *(f16x4*)&H[(nt * 32 + p0) * SH + hb + 8 * g] = o;
      }
    }
  }
}

__global__ __launch_bounds__(256, 2)
void mlp_fused(const float* __restrict__ points,
               LayerPtrs P,
               const f16x8* __restrict__ wf,
               const float* __restrict__ wsdf,
               const float* __restrict__ bsdf,
               float* __restrict__ out) {
  __shared__ __align__(16) _Float16 H[PTS * SH];   // 67584 B
  __shared__ __align__(16) _Float16 E[PTS * SE];   // 14336 B -> 81920 total, 2 blocks/CU
  const int tid = threadIdx.x;
  const int blk = blockIdx.x;

  const int lane = tid & 63;
  const int wg   = tid >> 6;          // wave -> hidden slice [64*wg, 64*wg+64)
  const int p0   = lane & 31;
  const int h    = lane >> 5;

  const f16x8* wb = wf + (wg * 2) * 64 + lane;   // + WOFF[l] + (kc*8+mt)*64
  const int WOFF[8] = {0,1536,9728,17920,26112,35840,44032,52224};

  // Prefetch L0 weights + bias tile before the (long) embedding VALU phase.
  WPre  wp = wpre(wb + WOFF[0]);
  BTile bt = bias_tile(P.b[0] + wg * 64, h);

  // ---- embedding into E: cols 0..38 = [sin(18)|cos(18)|xyz], 39..55 zero ----
  if (tid < PTS) {
    int p = blk * PTS + tid;
    float xyz[3] = {points[p * 3 + 0], points[p * 3 + 1], points[p * 3 + 2]};
    _Float16* row = &E[tid * SE];
#pragma unroll
    for (int c = 0; c < 3; ++c) {
      float fr = 1.f;
#pragma unroll
      for (int k = 0; k < 6; ++k) {
        float e = xyz[c] * fr;
        row[c * 6 + k]      = (_Float16)sinf(e);
        row[18 + c * 6 + k] = (_Float16)cosf(e);
        fr *= 2.f;
      }
      row[36 + c] = (_Float16)xyz[c];
    }
#pragma unroll
    for (int c = 39; c < SE; ++c) row[c] = (_Float16)0.f;
  }
  __syncthreads();

  const _Float16* e0 = &E[p0 * SE + h * 8];
  const _Float16* e1 = &E[(32 + p0) * SE + h * 8];
  const _Float16* e2 = &E[(64 + p0) * SE + h * 8];
  const _Float16* e3 = &E[(96 + p0) * SE + h * 8];
  const _Float16* h0 = &H[p0 * SH + h * 8];
  const _Float16* h1 = &H[(32 + p0) * SH + h * 8];
  const _Float16* h2 = &H[(64 + p0) * SH + h * 8];
  const _Float16* h3 = &H[(96 + p0) * SH + h * 8];

  f32x16 acc[2][4];

  // L0: read E, write H (disjoint -> no barrier between mm and store)
  mm<3, true, true, true>(wb + WOFF[0], e0, e1, e2, e3, acc, bt, wp);
  bt = bias_tile(P.b[1] + wg * 64, h);    // next-layer bias tile, pre-barrier
  wp = wpre(wb + WOFF[1]);                // next-layer kc0 weights
  store_act(acc, wg, lane, H);
  __syncthreads();

  // L1..L3: in-place H
#pragma unroll
  for (int l = 1; l < 4; ++l) {
    mm<16, true, true, true>(wb + WOFF[l], h0, h1, h2, h3, acc, bt, wp);
    bt = bias_tile(P.b[l + 1] + wg * 64, h);
    wp = wpre(wb + WOFF[l + 1]);
    __syncthreads();
    store_act(acc, wg, lane, H);
    __syncthreads();
  }

  // L4: concat input = E (3 kc, bias-C + prefetched) + H (16 kc, accumulate)
  mm<3, true, true, true>(wb + WOFF[4], e0, e1, e2, e3, acc, bt, wp);
  mm<16, false, false, true>(wb + WOFF[4] + 3 * 512, h0, h1, h2, h3, acc, bt, wp);
  bt = bias_tile(P.b[5] + wg * 64, h);
  wp = wpre(wb + WOFF[5]);
  __syncthreads();
  store_act(acc, wg, lane, H);
  __syncthreads();

  // L5..L6
#pragma unroll
  for (int l = 5; l < 7; ++l) {
    mm<16, true, true, true>(wb + WOFF[l], h0, h1, h2, h3, acc, bt, wp);
    bt = bias_tile(P.b[l + 1] + wg * 64, h);
    wp = wpre(wb + WOFF[l + 1]);
    __syncthreads();
    store_act(acc, wg, lane, H);
    __syncthreads();
  }

  // L7 + SDF head fused (non-pipelined mm: lower register pressure in the tail).
  // out[p] = sum_h relu(x7)[p][h]*wsdf[h] + bsdf.
  mm<16, true, true, false>(wb + WOFF[7], h0, h1, h2, h3, acc, bt, wp);
  {
    float part[4] = {0.f, 0.f, 0.f, 0.f};
    // Stream the wsdf gather quad-by-quad (4 live regs, not a 32-reg tile).
#pragma unroll
    for (int mt = 0; mt < 2; ++mt)
#pragma unroll
      for (int g = 0; g < 4; ++g) {
        f32x4 q = *(const f32x4*)&wsdf[wg * 64 + mt * 32 + 8 * g + 4 * h];
#pragma unroll
        for (int nt = 0; nt < 4; ++nt)
#pragma unroll
          for (int r = 0; r < 4; ++r)
            part[nt] += fmaxf(acc[mt][nt][4 * g + r], 0.f) * q[r];
      }
    // E space is dead (last read at L4) -> partial buffer [8][128] floats (4 KB)
    float* PB = (float*)E;
    __syncthreads();   // all L7 reads of H/E done before reuse of E
#pragma unroll
    for (int nt = 0; nt < 4; ++nt)
      PB[(wg * 2 + h) * 128 + nt * 32 + p0] = part[nt];
    __syncthreads();
    if (tid < PTS) {
      float s = bsdf[0];
#pragma unroll
      for (int j = 0; j < 8; ++j) s += PB[j * 128 + tid];
      out[blk * PTS + tid] = s;
    }
  }
}

extern "C" void kernel_launch(void* const* d_in, const int* in_sizes, int n_in,
                              void* d_out, int out_size, void* d_ws, size_t ws_size,
                              hipStream_t stream) {
  const float* points = (const float*)d_in[0];
  LayerPtrs P;
  for (int i = 0; i < 8; ++i) {
    P.w[i] = (const float*)d_in[1 + 2 * i];
    P.b[i] = (const float*)d_in[2 + 2 * i];
  }
  const float* wsdf = (const float*)d_in[17];
  const float* bsdf = (const float*)d_in[18];
  f16x8* wf = (f16x8*)d_ws;   // needs 966656 B

  int N = in_sizes[0] / 3;    // 262144
  prep_weights<<<236, 256, 0, stream>>>(P, wf);
  mlp_fused<<<N / PTS, 256, 0, stream>>>(points, P, wf, wsdf, bsdf, (float*)d_out);
}